// Round 5
// baseline (597.332 us; speedup 1.0000x reference)
//
#include <hip/hip_runtime.h>
#include <hip/hip_bf16.h>

// Problem constants
#define BATCH   65536
#define D       1024      // INPUT_DIM
#define L       100       // LATENT_DIM
#define C       21        // NUM_EMBEDDINGS
#define NPAD    112       // L padded to multiple of 16 for MFMA
#define RP      68        // LDS row pitch (floats): 272B = 17*16B -> rows stay 16B-aligned

typedef __bf16 bf16x8 __attribute__((ext_vector_type(8)));
typedef float  f32x4  __attribute__((ext_vector_type(4)));

// ---------------- workspace layout (bytes) ----------------
static constexpr size_t OFF_P  = 8192;
static constexpr size_t OFF_U  = OFF_P + (size_t)BATCH * 4;
static constexpr size_t OFF_T  = OFF_U + (size_t)C * D * 4;
static constexpr size_t OFF_R  = OFF_T + 128;
static constexpr size_t OFF_WB = OFF_R + (size_t)C * D * 4;

// ---------------- kernel 1: setup (tiny) ----------------
__global__ __launch_bounds__(256) void k_setup(
    const float* __restrict__ W_enc, const float* __restrict__ b_enc,
    const float* __restrict__ cb,    const float* __restrict__ W_dec,
    const float* __restrict__ b_dec,
    float* __restrict__ u, float* __restrict__ t, float* __restrict__ R,
    __bf16* __restrict__ Wb)
{
    int id = blockIdx.x * 256 + threadIdx.x;
    if (id < C * D) {                       // u[c][k] = sum_j cb[c][j] * W_enc[j][k]
        int c = id >> 10, k = id & 1023;
        float s = 0.f;
        for (int j = 0; j < L; j++) s += cb[c * L + j] * W_enc[j * D + k];
        u[id] = s;
    } else if (id < 2 * C * D) {            // R[c][k] = sum_j cb[c][j] * W_dec[k][j] + b_dec[k]
        int i2 = id - C * D;
        int c = i2 >> 10, k = i2 & 1023;
        float s = 0.f;
        for (int j = 0; j < L; j++) s += cb[c * L + j] * W_dec[k * L + j];
        R[i2] = s + b_dec[k];
    } else if (id < 2 * C * D + NPAD * D) { // Wb[n][k] bf16 (zero pad n>=100)
        int i3 = id - 2 * C * D;
        int n = i3 >> 10, k = i3 & 1023;
        Wb[i3] = (n < L) ? (__bf16)W_enc[n * D + k] : (__bf16)0.f;
    } else if (id < 2 * C * D + NPAD * D + C) { // t[c]
        int c = id - 2 * C * D - NPAD * D;
        float s = 0.f, b2 = 0.f;
        for (int j = 0; j < L; j++) {
            float cv = cb[c * L + j];
            s  += cv * cv;
            b2 += b_enc[j] * cv;
        }
        t[c] = s - 2.f * b2;
    }
}

// ---------------- kernel 2: FUSED, reg-staged LDS ----------------
// 64 rows/block, 4 waves, K in 64-col chunks (64x64 f32 = 16KB, dbuf'd in LDS
// with a 68-float row pitch). Staging is explicit reg-path:
//   wave w, call j, lane l loads x[row0 + w*16 + j*4 + (l>>4)][ch*64 + (l&15)*4 ..+3]
//   (global_load_dwordx4, 8 cache lines/instr) and ds_writes it to
//   xch[buf][w*16 + j*4 + (l>>4)][(l&15)*4] -- every address explicit, no
//   global_load_lds semantics in play, no swizzle (pad kills the worst conflicts).
// Loads for chunk ch+1 are issued BEFORE compute of chunk ch (T14); ds_write
// to the other buffer after compute; one __syncthreads per chunk.
// Score phase / MFMA phase / reduce are textually identical to the verified
// Round-2 kernel (same expression shapes and summation order).
__global__ __launch_bounds__(256, 4) void k_main(
    const float* __restrict__ x, const float* __restrict__ u,
    const float* __restrict__ t, const float* __restrict__ R,
    const __bf16* __restrict__ Wb, const float* __restrict__ b_enc,
    float* __restrict__ outR, float* __restrict__ outIdx,
    double* __restrict__ bsums)
{
    __shared__ float xch[2][64][RP];    // 34816 B, double-buffered chunk
    __shared__ float pbest[64];
    __shared__ int   idxs[64];
    __shared__ float bpart[16];
    // part[4][64][22] (22528 B) aliased onto xch -- only used AFTER the chunk
    // loop (final barrier of the loop separates the lifetimes).
    float* partf = &xch[0][0][0];
#define PART(w, l, c) partf[(((w) * 64 + (l)) * 22) + (c)]

    const int lane = threadIdx.x & 63;
    const int wave = __builtin_amdgcn_readfirstlane(threadIdx.x >> 6);
    const int row0 = blockIdx.x * 64;
    const int n15  = lane & 15;
    const int q    = lane >> 4;

    // staging geometry: wave w covers rows [w*16, w*16+16) of the block
    const int srow = wave * 16 + (lane >> 4);      // + j*4 per call, j=0..3
    const int sgr  = lane & 15;                    // 16B granule within row
    const float* sbase = x + (size_t)(row0 + srow) * D + sgr * 4;

    float sacc[C];
#pragma unroll
    for (int c = 0; c < C; c++) sacc[c] = 0.f;
    f32x4 zacc[7];
#pragma unroll
    for (int nt = 0; nt < 7; nt++) zacc[nt] = (f32x4){0.f, 0.f, 0.f, 0.f};

    const float* ub = u + wave * 16;               // wave-uniform base (s_load)
    const int mrow = wave * 16 + n15;              // MFMA A-row for this lane

    // ---- prologue: stage chunk 0 ----
    f32x4 stg[4];
#pragma unroll
    for (int j = 0; j < 4; j++) stg[j] = *(const f32x4*)(sbase + j * 4 * D);
#pragma unroll
    for (int j = 0; j < 4; j++) *(f32x4*)(&xch[0][srow + j * 4][sgr * 4]) = stg[j];
    __syncthreads();

    int cur = 0;
    for (int ch = 0; ch < 16; ch++) {
        const int k0 = ch * 64;
        // issue next chunk's global loads early (latency hides under compute)
        if (ch < 15) {
#pragma unroll
            for (int j = 0; j < 4; j++)
                stg[j] = *(const f32x4*)(sbase + j * 4 * D + (ch + 1) * 64);
        }

        // ---- score: lane=row, this wave's 16-col slice, u via scalar s_load ----
        const float* xb = &xch[cur][lane][0];
#pragma unroll
        for (int j2 = 0; j2 < 4; j2++) {
            f32x4 xv = *(const f32x4*)(xb + wave * 16 + j2 * 4);
#pragma unroll
            for (int c = 0; c < C; c++) {
                const float* uc = ub + c * D + k0 + j2 * 4;   // uniform -> s_load
                sacc[c] += xv[0] * uc[0] + xv[1] * uc[1] + xv[2] * uc[2] + xv[3] * uc[3];
            }
        }

        // ---- mfma: wave owns rows [wave*16, +16); A-frags from LDS ----
        const float* mb = &xch[cur][mrow][0];
#pragma unroll
        for (int ks = 0; ks < 2; ks++) {
            f32x4 a0 = *(const f32x4*)(mb + ks * 32 + q * 8);
            f32x4 a1 = *(const f32x4*)(mb + ks * 32 + q * 8 + 4);
            bf16x8 af;
            af[0] = (__bf16)a0[0]; af[1] = (__bf16)a0[1]; af[2] = (__bf16)a0[2]; af[3] = (__bf16)a0[3];
            af[4] = (__bf16)a1[0]; af[5] = (__bf16)a1[1]; af[6] = (__bf16)a1[2]; af[7] = (__bf16)a1[3];
#pragma unroll
            for (int nt = 0; nt < 7; nt++) {
                bf16x8 bfr = *(const bf16x8*)(Wb + (size_t)(nt * 16 + n15) * D + k0 + ks * 32 + q * 8);
                zacc[nt] = __builtin_amdgcn_mfma_f32_16x16x32_bf16(af, bfr, zacc[nt], 0, 0, 0);
            }
        }

        // ---- write next chunk into the other buffer (cur^1: nobody reads it) ----
        if (ch < 15) {
#pragma unroll
            for (int j = 0; j < 4; j++)
                *(f32x4*)(&xch[cur ^ 1][srow + j * 4][sgr * 4]) = stg[j];
        }
        __syncthreads();    // writes visible; all waves done reading xch[cur]
        cur ^= 1;
    }

    // ---- cross-wave score reduce (exact Round-2 form: parallel write, wave-0
    //      sums part[0]+part[1]+part[2]+part[3]) ----
#pragma unroll
    for (int c = 0; c < C; c++) PART(wave, lane, c) = sacc[c];
    __syncthreads();
    if (wave == 0) {
        float best = 3.0e38f;
        int   bi   = 0;
#pragma unroll
        for (int c = 0; c < C; c++) {
            float s = PART(0, lane, c) + PART(1, lane, c)
                    + PART(2, lane, c) + PART(3, lane, c);
            float score = t[c] - 2.0f * s;
            if (score < best) { best = score; bi = c; }   // first-min on ties
        }
        idxs[lane]          = bi;
        pbest[lane]         = best;         // == t_idx - 2 s_idx
        outIdx[row0 + lane] = (float)bi;
    }
    __syncthreads();

    // ---- ||z_e||^2 + p (same math/order as Round 2) ----
    float rn[4] = {0.f, 0.f, 0.f, 0.f};
#pragma unroll
    for (int nt = 0; nt < 7; nt++) {
        int col = nt * 16 + n15;
        float bn = (col < L) ? b_enc[col] : 0.f;
#pragma unroll
        for (int r = 0; r < 4; r++) {
            float z = zacc[nt][r] + bn;
            rn[r] += z * z;
        }
    }
#pragma unroll
    for (int off = 1; off < 16; off <<= 1) {
#pragma unroll
        for (int r = 0; r < 4; r++) rn[r] += __shfl_xor(rn[r], off, 64);
    }
    if (n15 == 0) {
        float s4 = 0.f;
#pragma unroll
        for (int r = 0; r < 4; r++) s4 += rn[r] + pbest[wave * 16 + q * 4 + r];
        bpart[wave * 4 + q] = s4;
    }
    __syncthreads();
    if (threadIdx.x == 0) {
        double bs = 0.0;
        for (int i = 0; i < 16; i++) bs += (double)bpart[i];
        bsums[blockIdx.x] = bs;
    }

    // ---- x_recon rows = R[idx]; non-temporal stores ----
    for (int r = 0; r < 64; r++) {
        int id = idxs[r];
        const f32x4 v = ((const f32x4*)(R + (size_t)id * D))[threadIdx.x];
        __builtin_nontemporal_store(v, ((f32x4*)(outR + (size_t)(row0 + r) * D)) + threadIdx.x);
    }
#undef PART
}

// ---------------- kernel 3: finalize loss ----------------
__global__ __launch_bounds__(256) void k_final(
    const double* __restrict__ bsums, float* __restrict__ out_loss)
{
    __shared__ double wsum[4];
    int t = threadIdx.x;
    double s = bsums[t] + bsums[t + 256] + bsums[t + 512] + bsums[t + 768];
    for (int off = 32; off; off >>= 1) s += __shfl_down(s, off, 64);
    if ((t & 63) == 0) wsum[t >> 6] = s;
    __syncthreads();
    if (t == 0) {
        double tot = wsum[0] + wsum[1] + wsum[2] + wsum[3];
        out_loss[0] = (float)(1.1 * tot / ((double)BATCH * (double)L));
    }
}

// ---------------- launch ----------------
extern "C" void kernel_launch(void* const* d_in, const int* in_sizes, int n_in,
                              void* d_out, int out_size, void* d_ws, size_t ws_size,
                              hipStream_t stream) {
    const float* x     = (const float*)d_in[0];
    const float* W_enc = (const float*)d_in[1];
    const float* b_enc = (const float*)d_in[2];
    const float* cb    = (const float*)d_in[3];
    const float* W_dec = (const float*)d_in[4];
    const float* b_dec = (const float*)d_in[5];

    char*   ws    = (char*)d_ws;
    double* bsums = (double*)ws;
    float*  u     = (float*)(ws + OFF_U);
    float*  t     = (float*)(ws + OFF_T);
    float*  R     = (float*)(ws + OFF_R);
    __bf16* Wb    = (__bf16*)(ws + OFF_WB);

    float* outR    = (float*)d_out;                       // 65536*1024
    float* outLoss = outR + (size_t)BATCH * D;            // 1
    float* outIdx  = outLoss + 1;                         // 65536 (as float values)

    k_setup<<<617, 256, 0, stream>>>(W_enc, b_enc, cb, W_dec, b_dec, u, t, R, Wb);
    k_main <<<BATCH / 64, 256, 0, stream>>>(x, u, t, R, Wb, b_enc, outR, outIdx, bsums);
    k_final<<<1, 256, 0, stream>>>(bsums, outLoss);
}